// Round 3
// baseline (70.514 us; speedup 1.0000x reference)
//
#include <hip/hip_runtime.h>
#include <math.h>

static constexpr int B   = 512;
static constexpr int NP  = 128;
static constexpr int NG  = 128;
static constexpr int TT  = 5;
static constexpr int NGI = NG * TT;          // 640 interpolated gt points
static constexpr float INV_CNT = 1.0f / (float)(B * NP * 2);

// Single fused kernel: one block per batch. 512 threads = (h in 0..3, p in
// 0..127): 4 threads per pred point, each scans 160 of 640 candidates via
// wave-uniform (broadcast) LDS b128 reads — 2 float2 candidates per read.
// Argmin as packed u32 key: (bits(d) & ~1023) | g  (valid: d >= 0, g < 1024);
// one v_min_u32 per candidate, ties -> smallest g (first occurrence).
// Block result is folded into d_out with one global_atomic_add_f32 — no
// second kernel, no partial array.
__global__ __launch_bounds__(512) void dm_fused(
    const float* __restrict__ pred,   // [B, NP, 2]
    const float* __restrict__ gt,     // [B, NG, 2]
    float* __restrict__ out)          // [1], pre-zeroed by memset node
{
    __shared__ float2   sgi[NGI];     // interpolated gt points
    __shared__ float    sgt[NG * 2];
    __shared__ unsigned skey[512];
    __shared__ float    swsum[2];

    const int b   = blockIdx.x;
    const int tid = threadIdx.x;

    // stage gt polygon (1 KB): one wave, float4-coalesced
    const float* gtb = gt + (size_t)b * NG * 2;
    if (tid < 64) ((float4*)sgt)[tid] = ((const float4*)gtb)[tid];
    __syncthreads();

    // interp[g = i*T + t] = gt[i]*st + gt[(i-1) mod NG]*(1-st)
    {
        int g = tid;
        #pragma unroll
        for (int r = 0; r < 2; ++r) {
            if (g < NGI) {
                const int i  = g / TT;
                const int t  = g - i * TT;
                const float st = (float)t * 0.2f;
                const float om = 1.0f - st;
                const int ip = (i == 0) ? (NG - 1) : (i - 1);
                sgi[g] = make_float2(sgt[2*i]   * st + sgt[2*ip]   * om,
                                     sgt[2*i+1] * st + sgt[2*ip+1] * om);
            }
            g += 512;
        }
    }
    __syncthreads();

    const int p = tid & (NP - 1);
    const int h = tid >> 7;                       // 0..3
    const float2 pv = ((const float2*)(pred + (size_t)b * NP * 2))[p];
    const float px = pv.x, py = pv.y;

    unsigned k0 = 0xFFFFFFFFu, k1 = 0xFFFFFFFFu;  // two chains for ILP
    const int c0 = h * (NGI / 4);                 // 160 candidates, even start
    const float4* sgi4 = (const float4*)sgi;
    #pragma unroll 8
    for (int j = 0; j < NGI / 8; ++j) {           // 80 b128 reads = 160 cands
        const float4 c = sgi4[(c0 >> 1) + j];
        const float dx0 = px - c.x, dy0 = py - c.y;
        const float d0  = fmaf(dy0, dy0, dx0 * dx0);
        k0 = min(k0, (__float_as_uint(d0) & 0xFFFFFC00u) | (unsigned)(c0 + 2*j));
        const float dx1 = px - c.z, dy1 = py - c.w;
        const float d1  = fmaf(dy1, dy1, dx1 * dx1);
        k1 = min(k1, (__float_as_uint(d1) & 0xFFFFFC00u) | (unsigned)(c0 + 2*j + 1));
    }
    skey[tid] = min(k0, k1);
    __syncthreads();

    if (tid < 128) {                              // waves 0,1 fully active
        const unsigned k = min(min(skey[tid],       skey[tid + 128]),
                               min(skey[tid + 256], skey[tid + 384]));
        const float2 m = sgi[k & 1023u];
        const float dx = fabsf(px - m.x);
        const float dy = fabsf(py - m.y);
        const float lx = (dx < 1.0f) ? 0.5f * dx * dx : dx - 0.5f;
        const float ly = (dy < 1.0f) ? 0.5f * dy * dy : dy - 0.5f;
        float v = lx + ly;
        #pragma unroll
        for (int off = 32; off > 0; off >>= 1) v += __shfl_down(v, off);
        if ((tid & 63) == 0) swsum[tid >> 6] = v;
    }
    __syncthreads();
    if (tid == 0) atomicAdd(out, (swsum[0] + swsum[1]) * INV_CNT);
}

extern "C" void kernel_launch(void* const* d_in, const int* in_sizes, int n_in,
                              void* d_out, int out_size, void* d_ws, size_t ws_size,
                              hipStream_t stream) {
    // inputs: [0] init_polys (unused), [1] pred_poly [512,128,2] f32,
    //         [2] gt_polys [512,128,2] f32
    const float* pred = (const float*)d_in[1];
    const float* gt   = (const float*)d_in[2];
    float* out        = (float*)d_out;

    // d_out is re-poisoned to 0xAA before every timed launch; zero it on
    // stream (capturable memset node), then accumulate with f32 atomics.
    hipMemsetAsync(out, 0, sizeof(float), stream);
    dm_fused<<<B, 512, 0, stream>>>(pred, gt, out);
}